// Round 13
// baseline (271.695 us; speedup 1.0000x reference)
//
#include <hip/hip_runtime.h>
#include <cstdint>
#include <cstddef>

#define NPIX 9216          // 96*96
#define NB 2
#define NC 256
#define RC 64
#define TK 16
#define NROWS (NB * NPIX)  // 18432
#define CT 128             // cols per LDS tile
#define NQ 24              // col splits per batch
#define ECOLS 384          // cols per split (3 tiles)
#define MAXC 128           // compact candidate slots per row
#define LCAP 48            // per-block per-row LDS candidate capacity
#define MARGIN 0.008f      // 2*e, e <= 2.01*2^-9 * ||a||*||b|| = 3.93e-3

typedef unsigned short ushort_t;
typedef unsigned int uint_t;
typedef __bf16 bf16x8 __attribute__((ext_vector_type(8)));
typedef float f32x4 __attribute__((ext_vector_type(4)));

__device__ __forceinline__ uint_t f2bf(float x) {
  uint_t u = __float_as_uint(x);
  return (u + 0x7FFFu + ((u >> 16) & 1u)) >> 16;
}

// monotone float->uint map (bigger float => bigger uint)
__device__ __forceinline__ uint_t ordu(float v) {
  uint_t u = __float_as_uint(v);
  return (u & 0x80000000u) ? ~u : (u | 0x80000000u);
}

// async global->LDS, 16B per lane. dest is wave-uniform base (HW adds lane*16).
#define GL2LDS(gsrc, ldst)                                                   \
  __builtin_amdgcn_global_load_lds(                                          \
      (const __attribute__((address_space(1))) uint_t*)(const void*)(gsrc),  \
      (__attribute__((address_space(3))) uint_t*)(void*)(ldst), 16, 0, 0)

// Stage one 128x64 bf16 tile (16 KB) via global_load_lds.
// LDS is linear [128][64]; source is pre-swizzled so that physical 16B-slot s
// of row r holds global slot s^(r&7) (rule #21: linear dest + swizzled source).
__device__ __forceinline__ void stage_tile(
    const ushort_t* __restrict__ gtile, ushort_t* shbuf, int tid) {
  const int wave = tid >> 6, l = tid & 63;
  const int lr = l >> 3;             // row within 8-row group
  const int ls = (l & 7) ^ lr;       // swizzled global slot
  const ushort_t* g = gtile + (size_t)lr * 64 + ls * 8;
#pragma unroll
  for (int i = 0; i < 4; ++i) {
    const int j = wave * 4 + i;      // instruction covers rows 8j..8j+7
    GL2LDS(g + (size_t)j * 512, shbuf + j * 512);  // 1024 B, wave-uniform dest
  }
}

// ---------------- K1: FUSED 1x1 conv reduce + normalize + bf16 hi ----------------
// grid: 288 blocks (64 rows each) x 256 threads; thread = (pixel_local, rq).
// (r12, frozen — measured neutral vs split pair, keeps one fewer dispatch)
__global__ __launch_bounds__(256) void k_reduce_norm(
    const float* __restrict__ x, const float* __restrict__ wr,
    float* __restrict__ nf, ushort_t* __restrict__ hi) {
  __shared__ float wl[NC * RC];  // 64 KB exactly: wl[c][r]
  const int tid = threadIdx.x;

  {  // transpose-stage w: thread t owns column c=t; coalesced global reads
    float4 tmp[16];
    const float* wcol = wr + tid;
#pragma unroll
    for (int j = 0; j < 16; ++j) {
      tmp[j].x = wcol[(size_t)(4 * j + 0) * NC];
      tmp[j].y = wcol[(size_t)(4 * j + 1) * NC];
      tmp[j].z = wcol[(size_t)(4 * j + 2) * NC];
      tmp[j].w = wcol[(size_t)(4 * j + 3) * NC];
    }
    float4* wrow = (float4*)(wl + (size_t)tid * RC);
#pragma unroll
    for (int j = 0; j < 16; ++j) wrow[j] = tmp[j];  // one-time conflicted write
  }

  const int pl = tid >> 2, rq = tid & 3;
  const int row = blockIdx.x * 64 + pl;   // 288*64 = NROWS
  const int b = row >= NPIX;
  const int n = row - b * NPIX;
  const float* xp = x + (size_t)b * NC * NPIX + n;
  __syncthreads();

  float s[16];
#pragma unroll
  for (int i = 0; i < 16; ++i) s[i] = 0.f;

#pragma unroll 1
  for (int half = 0; half < 4; ++half) {  // = old cq partials, in order
    float p4[16];
#pragma unroll
    for (int i = 0; i < 16; ++i) p4[i] = 0.f;
#pragma unroll 8
    for (int cl = 0; cl < 64; ++cl) {
      const int c = half * 64 + cl;
      const float xv = xp[(size_t)c * NPIX];              // 4-lane broadcast
      const float4* w4 = (const float4*)(wl + c * RC + rq * 16);
#pragma unroll
      for (int i = 0; i < 4; ++i) {
        float4 w = w4[i];
        p4[i * 4 + 0] += w.x * xv; p4[i * 4 + 1] += w.y * xv;
        p4[i * 4 + 2] += w.z * xv; p4[i * 4 + 3] += w.w * xv;
      }
    }
#pragma unroll
    for (int i = 0; i < 16; ++i) s[i] += p4[i];
  }

  float ssq = 0.f;
#pragma unroll
  for (int i = 0; i < 4; ++i) {  // group sums first (old normsplit order)
    const float g = s[4 * i] * s[4 * i] + s[4 * i + 1] * s[4 * i + 1] +
                    s[4 * i + 2] * s[4 * i + 2] + s[4 * i + 3] * s[4 * i + 3];
    ssq += g;
  }
  ssq += __shfl_xor(ssq, 1);
  ssq += __shfl_xor(ssq, 2);
  const float inv = 1.f / fmaxf(sqrtf(ssq), 1e-12f);
#pragma unroll
  for (int i = 0; i < 16; ++i) s[i] *= inv;

  float4* no = (float4*)(nf + (size_t)row * RC + rq * 16);
#pragma unroll
  for (int i = 0; i < 4; ++i)
    no[i] = make_float4(s[i * 4], s[i * 4 + 1], s[i * 4 + 2], s[i * 4 + 3]);

  uint_t hs[16];
#pragma unroll
  for (int i = 0; i < 16; ++i) hs[i] = f2bf(s[i]);
  uint4* ho = (uint4*)(hi + (size_t)row * RC + rq * 16);
#pragma unroll
  for (int h = 0; h < 2; ++h)
    ho[h] = make_uint4(hs[h*8+0] | (hs[h*8+1] << 16), hs[h*8+2] | (hs[h*8+3] << 16),
                       hs[h*8+4] | (hs[h*8+5] << 16), hs[h*8+6] | (hs[h*8+7] << 16));
}

// ---------------- K2a: pass A — full hi sims, per-lane chunk maxima ----------------
// grid: 144 rowblocks(128 rows) x 24 col-splits = 3456.
// Two tiles staged per drain (32 KB, static offsets): 3 syncs instead of 6.
__global__ __launch_bounds__(256) void k_sim_max(
    const ushort_t* __restrict__ nf_hi, float* __restrict__ tmax) {
  __shared__ ushort_t sh[2 * CT * 64];  // 32 KB linear
  const int rb = blockIdx.x / NQ, q = blockIdx.x % NQ;
  const int tid = threadIdx.x, wave = tid >> 6, lane = tid & 63;
  const int n = lane & 15, quad = lane >> 4;
  const int r0 = rb * 128 + wave * 32 + n, r1 = r0 + 16;
  const int b = rb >= 72;
  const size_t cbase = (size_t)b * NPIX;
  const int x0 = (quad ^ (n & 7)) * 8;        // swizzled slot offsets (ushorts)
  const int x1 = ((quad + 4) ^ (n & 7)) * 8;

  const bf16x8 bh00 = *(const bf16x8*)(nf_hi + (size_t)r0 * 64 + quad * 8);
  const bf16x8 bh01 = *(const bf16x8*)(nf_hi + (size_t)r0 * 64 + 32 + quad * 8);
  const bf16x8 bh10 = *(const bf16x8*)(nf_hi + (size_t)r1 * 64 + quad * 8);
  const bf16x8 bh11 = *(const bf16x8*)(nf_hi + (size_t)r1 * 64 + 32 + quad * 8);

  float cm0 = -1e30f, cm1 = -1e30f;
  const ushort_t* gtile = nf_hi + (cbase + q * ECOLS) * 64;

  auto compute = [&](const ushort_t* shc) {
#pragma unroll
    for (int st = 0; st < 8; ++st) {
      const ushort_t* ap = shc + (st * 16 + n) * 64;
      bf16x8 ah0 = *(const bf16x8*)(ap + x0);
      bf16x8 ah1 = *(const bf16x8*)(ap + x1);
      f32x4 z = {0.f, 0.f, 0.f, 0.f};
      f32x4 a0 = __builtin_amdgcn_mfma_f32_16x16x32_bf16(ah0, bh00, z, 0, 0, 0);
      a0 = __builtin_amdgcn_mfma_f32_16x16x32_bf16(ah1, bh01, a0, 0, 0, 0);
      f32x4 a1 = __builtin_amdgcn_mfma_f32_16x16x32_bf16(ah0, bh10, z, 0, 0, 0);
      a1 = __builtin_amdgcn_mfma_f32_16x16x32_bf16(ah1, bh11, a1, 0, 0, 0);
      const float m0 = fmaxf(fmaxf(a0[0], a0[1]), fmaxf(a0[2], a0[3]));
      const float m1 = fmaxf(fmaxf(a1[0], a1[1]), fmaxf(a1[2], a1[3]));
      cm0 = fmaxf(cm0, m0);
      cm1 = fmaxf(cm1, m1);
    }
  };

  stage_tile(gtile, sh, tid);
  stage_tile(gtile + CT * 64, sh + CT * 64, tid);
  __syncthreads();          // drains both tiles' DMA
  compute(sh);
  compute(sh + CT * 64);
  __syncthreads();          // readers done
  stage_tile(gtile + 2 * CT * 64, sh, tid);
  __syncthreads();          // drain tile 2
  compute(sh);

  // one chunk (96... = 3*128 cols) per stream: stream id = q*4+quad
  tmax[(size_t)r0 * 96 + q * 4 + quad] = cm0;
  tmax[(size_t)r1 * 96 + q * 4 + quad] = cm1;
}

// ---------------- K2b: threshold = 16th largest of 96 chunk maxima - margin ----------------
// Also zeroes rowcnt (memset dispatch folded in; thresh runs before collect).
__global__ __launch_bounds__(256) void k_thresh(
    const float* __restrict__ tmax, float* __restrict__ Tb,
    int* __restrict__ rowcnt) {
  const int wave = threadIdx.x >> 6, lane = threadIdx.x & 63;
  const int row = blockIdx.x * 4 + wave;
  const float* tp = tmax + (size_t)row * 96;
  float v0 = tp[lane];
  float v1 = (lane < 32) ? tp[64 + lane] : -1e30f;
  float m = -1e30f;
#pragma unroll
  for (int k = 0; k < TK; ++k) {
    float c = fmaxf(v0, v1);
#pragma unroll
    for (int d = 1; d < 64; d <<= 1) c = fmaxf(c, __shfl_xor(c, d));
    m = c;
    if (v0 == m) v0 = -1e30f;  // killing duplicates only lowers T: safe
    if (v1 == m) v1 = -1e30f;
  }
  if (lane == 0) {
    Tb[row] = m - MARGIN;
    rowcnt[row] = 0;
  }
}

// ---------------- K2c: pass B — full hi sims, collect cols with s_hi >= T ----------------
// Two tiles per drain (4 syncs vs 6); max-tree early-out; per-row LDS lists;
// one global atomicAdd per row per block at flush.
__global__ __launch_bounds__(256) void k_collect(
    const ushort_t* __restrict__ nf_hi, const float* __restrict__ Tb,
    int* __restrict__ cidx, int* __restrict__ rowcnt) {
  __shared__ ushort_t sh[2 * CT * 64];      // 32 KB staging
  __shared__ ushort_t lst[128][LCAP + 1];   // 12.3 KB per-row candidate lists
  __shared__ int lcnt[128];                 // 512 B
  const int rb = blockIdx.x / NQ, q = blockIdx.x % NQ;
  const int tid = threadIdx.x, wave = tid >> 6, lane = tid & 63;
  const int n = lane & 15, quad = lane >> 4;
  const int rl0 = wave * 32 + n, rl1 = rl0 + 16;  // row-local ids in [0,128)
  const int r0 = rb * 128 + rl0, r1 = r0 + 16;
  const int b = rb >= 72;
  const size_t cbase = (size_t)b * NPIX;
  const int x0 = (quad ^ (n & 7)) * 8;
  const int x1 = ((quad + 4) ^ (n & 7)) * 8;

  if (tid < 128) lcnt[tid] = 0;

  const bf16x8 bh00 = *(const bf16x8*)(nf_hi + (size_t)r0 * 64 + quad * 8);
  const bf16x8 bh01 = *(const bf16x8*)(nf_hi + (size_t)r0 * 64 + 32 + quad * 8);
  const bf16x8 bh10 = *(const bf16x8*)(nf_hi + (size_t)r1 * 64 + quad * 8);
  const bf16x8 bh11 = *(const bf16x8*)(nf_hi + (size_t)r1 * 64 + 32 + quad * 8);

  const float T0 = Tb[r0], T1 = Tb[r1];
  const ushort_t* gtile = nf_hi + (cbase + q * ECOLS) * 64;

  auto compute = [&](const ushort_t* shc, int cb) {
#pragma unroll
    for (int st = 0; st < 8; ++st) {
      const ushort_t* ap = shc + (st * 16 + n) * 64;
      bf16x8 ah0 = *(const bf16x8*)(ap + x0);
      bf16x8 ah1 = *(const bf16x8*)(ap + x1);
      f32x4 z = {0.f, 0.f, 0.f, 0.f};
      f32x4 a0 = __builtin_amdgcn_mfma_f32_16x16x32_bf16(ah0, bh00, z, 0, 0, 0);
      a0 = __builtin_amdgcn_mfma_f32_16x16x32_bf16(ah1, bh01, a0, 0, 0, 0);
      f32x4 a1 = __builtin_amdgcn_mfma_f32_16x16x32_bf16(ah0, bh10, z, 0, 0, 0);
      a1 = __builtin_amdgcn_mfma_f32_16x16x32_bf16(ah1, bh11, a1, 0, 0, 0);

      const int c0 = cb + st * 16 + quad * 4;
      const float mx0 = fmaxf(fmaxf(a0[0], a0[1]), fmaxf(a0[2], a0[3]));
      if (mx0 >= T0) {
        const int m0 = (a0[0] >= T0) | ((a0[1] >= T0) << 1) |
                       ((a0[2] >= T0) << 2) | ((a0[3] >= T0) << 3);
        int slot = atomicAdd(&lcnt[rl0], __popc(m0));  // LDS atomic
#pragma unroll
        for (int r = 0; r < 4; ++r)
          if (m0 & (1 << r)) {
            if (slot < LCAP) lst[rl0][slot] = (ushort_t)(c0 + r);
            ++slot;
          }
      }
      const float mx1 = fmaxf(fmaxf(a1[0], a1[1]), fmaxf(a1[2], a1[3]));
      if (mx1 >= T1) {
        const int m1 = (a1[0] >= T1) | ((a1[1] >= T1) << 1) |
                       ((a1[2] >= T1) << 2) | ((a1[3] >= T1) << 3);
        int slot = atomicAdd(&lcnt[rl1], __popc(m1));
#pragma unroll
        for (int r = 0; r < 4; ++r)
          if (m1 & (1 << r)) {
            if (slot < LCAP) lst[rl1][slot] = (ushort_t)(c0 + r);
            ++slot;
          }
      }
    }
  };

  stage_tile(gtile, sh, tid);
  stage_tile(gtile + CT * 64, sh + CT * 64, tid);
  __syncthreads();          // drains both tiles' DMA (also covers lcnt init)
  compute(sh, q * ECOLS);
  compute(sh + CT * 64, q * ECOLS + CT);
  __syncthreads();          // readers done
  stage_tile(gtile + 2 * CT * 64, sh, tid);
  __syncthreads();          // drain tile 2
  compute(sh, q * ECOLS + 2 * CT);
  __syncthreads();          // all lst writes visible for flush

  // flush: one global reservation per row, 128 rows by threads 0..127
  if (tid < 128) {
    const int row = rb * 128 + tid;
    const int cnt = min(lcnt[tid], LCAP);
    int base = atomicAdd(rowcnt + row, cnt);
    for (int j = 0; j < cnt; ++j) {
      const int gs = base + j;
      if (gs < MAXC) cidx[(size_t)row * MAXC + gs] = (int)lst[tid][j];
    }
  }
}

// ---------------- K3: exact fp32 dots on candidates + top-16 + gather + mean ----------------
// wave per row; grid NROWS/4 = 4608 blocks x 4 waves. Barrier-free waves.
// (r11, frozen)
__global__ __launch_bounds__(256) void k_merge_gather(
    const float* __restrict__ nf, const int* __restrict__ cidx,
    const int* __restrict__ rowcnt, float* __restrict__ corr) {
  __shared__ ushort_t selc[4][TK];
  const int wave = threadIdx.x >> 6, lane = threadIdx.x & 63;
  const int row = blockIdx.x * 4 + wave;
  const int b = row >= NPIX;
  const int rl = row - b * NPIX;
  const float* nfb = nf + (size_t)b * NPIX * RC;

  // issue earliest: candidate index + count (everything downstream depends)
  const int cv = cidx[(size_t)row * MAXC + lane];
  const int C = min(rowcnt[row], MAXC);

  if (lane < TK) selc[wave][lane] = (ushort_t)rl;  // same-wave pad init

  float4 rv[16];
  const float4* r4 = (const float4*)(nf + (size_t)row * RC);
#pragma unroll
  for (int i = 0; i < 16; ++i) rv[i] = r4[i];  // broadcast loads

  unsigned long long k0 = 0;
  int c0;
  {
    c0 = (lane < C) ? cv : rl;
    const float4* g = (const float4*)(nfb + (size_t)c0 * RC);
    float s = 0.f;
#pragma unroll
    for (int i = 0; i < 16; ++i) {
      float4 a = g[i];
      s += a.x * rv[i].x + a.y * rv[i].y + a.z * rv[i].z + a.w * rv[i].w;
    }
    if (lane < C)
      k0 = ((unsigned long long)ordu(s) << 32) | (uint_t)(~(uint_t)c0);
  }

  if (C <= 64) {  // common path, wave-uniform branch
    unsigned long long thr = 0;
#pragma unroll
    for (int bit = 63; bit >= 0; --bit) {
      const unsigned long long cand = thr | (1ull << bit);
      if (__popcll(__ballot(k0 >= cand)) >= TK) thr = cand;
    }
    if (thr != 0) {
      const unsigned long long ml = (lane == 0) ? 0ull : (~0ull >> (64 - lane));
      const unsigned long long b0 = __ballot(k0 >= thr);
      if (k0 >= thr) {
        const int r = __popcll(b0 & ml);
        if (r < TK) selc[wave][r] = (ushort_t)c0;
      }
    }
  } else {  // heavy rows, rare: second phase
    unsigned long long k1 = 0;
    int c1;
    {
      c1 = (64 + lane < C) ? cidx[(size_t)row * MAXC + 64 + lane] : rl;
      const float4* g = (const float4*)(nfb + (size_t)c1 * RC);
      float s = 0.f;
#pragma unroll
      for (int i = 0; i < 16; ++i) {
        float4 a = g[i];
        s += a.x * rv[i].x + a.y * rv[i].y + a.z * rv[i].z + a.w * rv[i].w;
      }
      if (64 + lane < C)
        k1 = ((unsigned long long)ordu(s) << 32) | (uint_t)(~(uint_t)c1);
    }
    unsigned long long thr = 0;
#pragma unroll
    for (int bit = 63; bit >= 0; --bit) {
      const unsigned long long cand = thr | (1ull << bit);
      const int cnt = __popcll(__ballot(k0 >= cand)) + __popcll(__ballot(k1 >= cand));
      if (cnt >= TK) thr = cand;
    }
    if (thr != 0) {
      const unsigned long long ml = (lane == 0) ? 0ull : (~0ull >> (64 - lane));
      const unsigned long long b0 = __ballot(k0 >= thr);
      const unsigned long long b1 = __ballot(k1 >= thr);
      const int n0 = __popcll(b0);
      if (k0 >= thr) {
        const int r = __popcll(b0 & ml);
        if (r < TK) selc[wave][r] = (ushort_t)c0;
      }
      if (k1 >= thr) {
        const int r = n0 + __popcll(b1 & ml);
        if (r < TK) selc[wave][r] = (ushort_t)c1;
      }
    }
  }

  // wave-order LDS: writes above precede reads below in program order;
  // compiler fence pins ordering (no cross-wave sharing -> no barrier).
  asm volatile("" ::: "memory");

  float acc = 0.f;
#pragma unroll
  for (int t = 0; t < TK; ++t)
    acc += nfb[(size_t)selc[wave][t] * RC + lane];  // coalesced 256B per t
  corr[(size_t)row * RC + lane] = acc * 0.0625f;
}

// ---------------- K4: proj back to C channels + residual add ----------------
// grid: 144 pixgroups(128) x 8 channel-eighths = 1152 blocks x 128 threads
// (r12, frozen)
__global__ __launch_bounds__(128) void k_proj_add(
    const float* __restrict__ x, const float* __restrict__ wp,
    const float* __restrict__ corr, float* __restrict__ out) {
  const int pg = blockIdx.x >> 3, cq = blockIdx.x & 7;
  const int tid = threadIdx.x;  // 0..127

  __shared__ float wl[32 * RC];  // 8 KB
  {
    const float4* src = (const float4*)(wp + (size_t)cq * 32 * RC);
    float4* dst = (float4*)wl;
#pragma unroll
    for (int i = 0; i < 4; ++i) dst[i * 128 + tid] = src[i * 128 + tid];
  }

  const int p = pg * 128 + tid;  // 144*128 = NROWS
  const int b = p >= NPIX;
  const int n = p - b * NPIX;

  float4 cr[16];
  const float4* c4 = (const float4*)(corr + (size_t)p * RC);
#pragma unroll
  for (int i = 0; i < 16; ++i) cr[i] = c4[i];
  __syncthreads();

  const size_t xb = (size_t)b * NC * NPIX + n;
  for (int cl = 0; cl < 32; ++cl) {
    const float4* w4 = (const float4*)(wl + cl * RC);  // broadcast
    float s = 0.f;
#pragma unroll
    for (int i = 0; i < 16; ++i) {
      float4 w = w4[i];
      s += w.x * cr[i].x + w.y * cr[i].y + w.z * cr[i].z + w.w * cr[i].w;
    }
    const int c = cq * 32 + cl;
    const size_t oi = xb + (size_t)c * NPIX;
    out[oi] = x[oi] + s;  // coalesced
  }
}

extern "C" void kernel_launch(void* const* d_in, const int* in_sizes, int n_in,
                              void* d_out, int out_size, void* d_ws, size_t ws_size,
                              hipStream_t stream) {
  const float* x = (const float*)d_in[0];
  const float* wr = (const float*)d_in[1];
  const float* wp = (const float*)d_in[2];
  float* out = (float*)d_out;

  char* ws = (char*)d_ws;
  // region1 (18,874,368 B) time-shares: tmax (sim_max->thresh, 7.1 MB),
  // corr (merge->proj).
  float* tmax = (float*)ws;
  float* corr = (float*)ws;
  float* nf = (float*)(ws + 18874368);
  ushort_t* nf_hi = (ushort_t*)(ws + 23592960);
  float* Tb = (float*)(ws + 25952256);
  int* rowcnt = (int*)(ws + 26025984);
  int* cidx = (int*)(ws + 26099712);
  // total 35,536,896 B

  hipLaunchKernelGGL(k_reduce_norm, dim3(288), dim3(256), 0, stream, x, wr, nf, nf_hi);
  hipLaunchKernelGGL(k_sim_max, dim3(144 * NQ), dim3(256), 0, stream, nf_hi, tmax);
  hipLaunchKernelGGL(k_thresh, dim3(NROWS / 4), dim3(256), 0, stream, tmax, Tb, rowcnt);
  hipLaunchKernelGGL(k_collect, dim3(144 * NQ), dim3(256), 0, stream,
                     nf_hi, Tb, cidx, rowcnt);
  hipLaunchKernelGGL(k_merge_gather, dim3(NROWS / 4), dim3(256), 0, stream,
                     nf, cidx, rowcnt, corr);
  hipLaunchKernelGGL(k_proj_add, dim3(1152), dim3(128), 0, stream, x, wp, corr, out);
}

// Round 14
// 255.210 us; speedup vs baseline: 1.0646x; 1.0646x over previous
//
#include <hip/hip_runtime.h>
#include <cstdint>
#include <cstddef>

#define NPIX 9216          // 96*96
#define NB 2
#define NC 256
#define RC 64
#define TK 16
#define NROWS (NB * NPIX)  // 18432
#define CT 128             // cols per LDS tile
#define NQ 24              // col splits per batch
#define ECOLS 384          // cols per split (3 tiles)
#define NTE 3              // tiles per split (= 1 chunk stream)
#define MAXC 128           // compact candidate slots per row
#define LCAP 32            // per-block per-row LDS candidate capacity
#define MARGIN 0.008f      // 2*e, e <= 2.01*2^-9 * ||a||*||b|| = 3.93e-3

typedef unsigned short ushort_t;
typedef unsigned int uint_t;
typedef __bf16 bf16x8 __attribute__((ext_vector_type(8)));
typedef float f32x4 __attribute__((ext_vector_type(4)));

__device__ __forceinline__ uint_t f2bf(float x) {
  uint_t u = __float_as_uint(x);
  return (u + 0x7FFFu + ((u >> 16) & 1u)) >> 16;
}

// monotone float->uint map (bigger float => bigger uint)
__device__ __forceinline__ uint_t ordu(float v) {
  uint_t u = __float_as_uint(v);
  return (u & 0x80000000u) ? ~u : (u | 0x80000000u);
}

// async global->LDS, 16B per lane. dest is wave-uniform base (HW adds lane*16).
#define GL2LDS(gsrc, ldst)                                                   \
  __builtin_amdgcn_global_load_lds(                                          \
      (const __attribute__((address_space(1))) uint_t*)(const void*)(gsrc),  \
      (__attribute__((address_space(3))) uint_t*)(void*)(ldst), 16, 0, 0)

// Stage one 128x64 bf16 tile (16 KB) via global_load_lds.
// LDS is linear [128][64]; source is pre-swizzled so that physical 16B-slot s
// of row r holds global slot s^(r&7) (rule #21: linear dest + swizzled source).
__device__ __forceinline__ void stage_tile(
    const ushort_t* __restrict__ gtile, ushort_t* shbuf, int tid) {
  const int wave = tid >> 6, l = tid & 63;
  const int lr = l >> 3;             // row within 8-row group
  const int ls = (l & 7) ^ lr;       // swizzled global slot
  const ushort_t* g = gtile + (size_t)lr * 64 + ls * 8;
#pragma unroll
  for (int i = 0; i < 4; ++i) {
    const int j = wave * 4 + i;      // instruction covers rows 8j..8j+7
    GL2LDS(g + (size_t)j * 512, shbuf + j * 512);  // 1024 B, wave-uniform dest
  }
}

// ---------------- K1: FUSED 1x1 conv reduce + normalize + bf16 hi ----------------
// grid: 288 blocks (64 rows each) x 256 threads; thread = (pixel_local, rq).
// (r12, frozen)
__global__ __launch_bounds__(256) void k_reduce_norm(
    const float* __restrict__ x, const float* __restrict__ wr,
    float* __restrict__ nf, ushort_t* __restrict__ hi) {
  __shared__ float wl[NC * RC];  // 64 KB exactly: wl[c][r]
  const int tid = threadIdx.x;

  {  // transpose-stage w: thread t owns column c=t; coalesced global reads
    float4 tmp[16];
    const float* wcol = wr + tid;
#pragma unroll
    for (int j = 0; j < 16; ++j) {
      tmp[j].x = wcol[(size_t)(4 * j + 0) * NC];
      tmp[j].y = wcol[(size_t)(4 * j + 1) * NC];
      tmp[j].z = wcol[(size_t)(4 * j + 2) * NC];
      tmp[j].w = wcol[(size_t)(4 * j + 3) * NC];
    }
    float4* wrow = (float4*)(wl + (size_t)tid * RC);
#pragma unroll
    for (int j = 0; j < 16; ++j) wrow[j] = tmp[j];  // one-time conflicted write
  }

  const int pl = tid >> 2, rq = tid & 3;
  const int row = blockIdx.x * 64 + pl;   // 288*64 = NROWS
  const int b = row >= NPIX;
  const int n = row - b * NPIX;
  const float* xp = x + (size_t)b * NC * NPIX + n;
  __syncthreads();

  float s[16];
#pragma unroll
  for (int i = 0; i < 16; ++i) s[i] = 0.f;

#pragma unroll 1
  for (int half = 0; half < 4; ++half) {  // = old cq partials, in order
    float p4[16];
#pragma unroll
    for (int i = 0; i < 16; ++i) p4[i] = 0.f;
#pragma unroll 8
    for (int cl = 0; cl < 64; ++cl) {
      const int c = half * 64 + cl;
      const float xv = xp[(size_t)c * NPIX];              // 4-lane broadcast
      const float4* w4 = (const float4*)(wl + c * RC + rq * 16);
#pragma unroll
      for (int i = 0; i < 4; ++i) {
        float4 w = w4[i];
        p4[i * 4 + 0] += w.x * xv; p4[i * 4 + 1] += w.y * xv;
        p4[i * 4 + 2] += w.z * xv; p4[i * 4 + 3] += w.w * xv;
      }
    }
#pragma unroll
    for (int i = 0; i < 16; ++i) s[i] += p4[i];
  }

  float ssq = 0.f;
#pragma unroll
  for (int i = 0; i < 4; ++i) {  // group sums first (old normsplit order)
    const float g = s[4 * i] * s[4 * i] + s[4 * i + 1] * s[4 * i + 1] +
                    s[4 * i + 2] * s[4 * i + 2] + s[4 * i + 3] * s[4 * i + 3];
    ssq += g;
  }
  ssq += __shfl_xor(ssq, 1);
  ssq += __shfl_xor(ssq, 2);
  const float inv = 1.f / fmaxf(sqrtf(ssq), 1e-12f);
#pragma unroll
  for (int i = 0; i < 16; ++i) s[i] *= inv;

  float4* no = (float4*)(nf + (size_t)row * RC + rq * 16);
#pragma unroll
  for (int i = 0; i < 4; ++i)
    no[i] = make_float4(s[i * 4], s[i * 4 + 1], s[i * 4 + 2], s[i * 4 + 3]);

  uint_t hs[16];
#pragma unroll
  for (int i = 0; i < 16; ++i) hs[i] = f2bf(s[i]);
  uint4* ho = (uint4*)(hi + (size_t)row * RC + rq * 16);
#pragma unroll
  for (int h = 0; h < 2; ++h)
    ho[h] = make_uint4(hs[h*8+0] | (hs[h*8+1] << 16), hs[h*8+2] | (hs[h*8+3] << 16),
                       hs[h*8+4] | (hs[h*8+5] << 16), hs[h*8+6] | (hs[h*8+7] << 16));
}

// ---------------- K2a: pass A — full hi sims, per-lane chunk maxima ----------------
// grid: 144 rowblocks(128 rows) x 24 col-splits = 3456. (r12 single-tile
// staging restored — r13's 2-tile variant cost occupancy and regressed.)
__global__ __launch_bounds__(256) void k_sim_max(
    const ushort_t* __restrict__ nf_hi, float* __restrict__ tmax) {
  __shared__ ushort_t sh[CT * 64];  // 16 KB linear
  const int rb = blockIdx.x / NQ, q = blockIdx.x % NQ;
  const int tid = threadIdx.x, wave = tid >> 6, lane = tid & 63;
  const int n = lane & 15, quad = lane >> 4;
  const int r0 = rb * 128 + wave * 32 + n, r1 = r0 + 16;
  const int b = rb >= 72;
  const size_t cbase = (size_t)b * NPIX;
  const int x0 = (quad ^ (n & 7)) * 8;        // swizzled slot offsets (ushorts)
  const int x1 = ((quad + 4) ^ (n & 7)) * 8;

  const bf16x8 bh00 = *(const bf16x8*)(nf_hi + (size_t)r0 * 64 + quad * 8);
  const bf16x8 bh01 = *(const bf16x8*)(nf_hi + (size_t)r0 * 64 + 32 + quad * 8);
  const bf16x8 bh10 = *(const bf16x8*)(nf_hi + (size_t)r1 * 64 + quad * 8);
  const bf16x8 bh11 = *(const bf16x8*)(nf_hi + (size_t)r1 * 64 + 32 + quad * 8);

  float cm0 = -1e30f, cm1 = -1e30f;
  const ushort_t* gtile = nf_hi + (cbase + q * ECOLS) * 64;

  for (int t = 0; t < NTE; ++t) {
    stage_tile(gtile, sh, tid);
    gtile += CT * 64;
    __syncthreads();  // drains vmcnt(0): tile resident

#pragma unroll
    for (int st = 0; st < 8; ++st) {
      const ushort_t* ap = sh + (st * 16 + n) * 64;
      bf16x8 ah0 = *(const bf16x8*)(ap + x0);
      bf16x8 ah1 = *(const bf16x8*)(ap + x1);
      f32x4 z = {0.f, 0.f, 0.f, 0.f};
      f32x4 a0 = __builtin_amdgcn_mfma_f32_16x16x32_bf16(ah0, bh00, z, 0, 0, 0);
      a0 = __builtin_amdgcn_mfma_f32_16x16x32_bf16(ah1, bh01, a0, 0, 0, 0);
      f32x4 a1 = __builtin_amdgcn_mfma_f32_16x16x32_bf16(ah0, bh10, z, 0, 0, 0);
      a1 = __builtin_amdgcn_mfma_f32_16x16x32_bf16(ah1, bh11, a1, 0, 0, 0);
      const float m0 = fmaxf(fmaxf(a0[0], a0[1]), fmaxf(a0[2], a0[3]));
      const float m1 = fmaxf(fmaxf(a1[0], a1[1]), fmaxf(a1[2], a1[3]));
      cm0 = fmaxf(cm0, m0);
      cm1 = fmaxf(cm1, m1);
    }
    __syncthreads();  // readers done before next stage overwrites
  }
  // one chunk (96 cols) per stream: stream id = q*4+quad
  tmax[(size_t)r0 * 96 + q * 4 + quad] = cm0;
  tmax[(size_t)r1 * 96 + q * 4 + quad] = cm1;
}

// ---------------- K2b: threshold = 16th largest of 96 chunk maxima - margin ----------------
// Also zeroes rowcnt (memset dispatch folded in; thresh runs before collect).
__global__ __launch_bounds__(256) void k_thresh(
    const float* __restrict__ tmax, float* __restrict__ Tb,
    int* __restrict__ rowcnt) {
  const int wave = threadIdx.x >> 6, lane = threadIdx.x & 63;
  const int row = blockIdx.x * 4 + wave;
  const float* tp = tmax + (size_t)row * 96;
  float v0 = tp[lane];
  float v1 = (lane < 32) ? tp[64 + lane] : -1e30f;
  float m = -1e30f;
#pragma unroll
  for (int k = 0; k < TK; ++k) {
    float c = fmaxf(v0, v1);
#pragma unroll
    for (int d = 1; d < 64; d <<= 1) c = fmaxf(c, __shfl_xor(c, d));
    m = c;
    if (v0 == m) v0 = -1e30f;  // killing duplicates only lowers T: safe
    if (v1 == m) v1 = -1e30f;
  }
  if (lane == 0) {
    Tb[row] = m - MARGIN;
    rowcnt[row] = 0;
  }
}

// ---------------- K2c: pass B — full hi sims, collect cols with s_hi >= T ----------------
// Single-tile staging (r12); max-tree early-out; per-row LDS lists (LCAP 32
// -> total LDS 25.4 KB -> 6 blocks/CU); one global atomicAdd per row per
// block at flush.
__global__ __launch_bounds__(256) void k_collect(
    const ushort_t* __restrict__ nf_hi, const float* __restrict__ Tb,
    int* __restrict__ cidx, int* __restrict__ rowcnt) {
  __shared__ ushort_t sh[CT * 64];          // 16 KB staging
  __shared__ ushort_t lst[128][LCAP + 1];   // 8.4 KB per-row candidate lists
  __shared__ int lcnt[128];                 // 512 B
  const int rb = blockIdx.x / NQ, q = blockIdx.x % NQ;
  const int tid = threadIdx.x, wave = tid >> 6, lane = tid & 63;
  const int n = lane & 15, quad = lane >> 4;
  const int rl0 = wave * 32 + n, rl1 = rl0 + 16;  // row-local ids in [0,128)
  const int r0 = rb * 128 + rl0, r1 = r0 + 16;
  const int b = rb >= 72;
  const size_t cbase = (size_t)b * NPIX;
  const int x0 = (quad ^ (n & 7)) * 8;
  const int x1 = ((quad + 4) ^ (n & 7)) * 8;

  if (tid < 128) lcnt[tid] = 0;

  const bf16x8 bh00 = *(const bf16x8*)(nf_hi + (size_t)r0 * 64 + quad * 8);
  const bf16x8 bh01 = *(const bf16x8*)(nf_hi + (size_t)r0 * 64 + 32 + quad * 8);
  const bf16x8 bh10 = *(const bf16x8*)(nf_hi + (size_t)r1 * 64 + quad * 8);
  const bf16x8 bh11 = *(const bf16x8*)(nf_hi + (size_t)r1 * 64 + 32 + quad * 8);

  const float T0 = Tb[r0], T1 = Tb[r1];
  const ushort_t* gtile = nf_hi + (cbase + q * ECOLS) * 64;

  for (int t = 0; t < NTE; ++t) {
    const int cb = q * ECOLS + t * CT;
    stage_tile(gtile, sh, tid);
    gtile += CT * 64;
    __syncthreads();  // vmcnt drained: tile resident (also covers lcnt init)

#pragma unroll
    for (int st = 0; st < 8; ++st) {
      const ushort_t* ap = sh + (st * 16 + n) * 64;
      bf16x8 ah0 = *(const bf16x8*)(ap + x0);
      bf16x8 ah1 = *(const bf16x8*)(ap + x1);
      f32x4 z = {0.f, 0.f, 0.f, 0.f};
      f32x4 a0 = __builtin_amdgcn_mfma_f32_16x16x32_bf16(ah0, bh00, z, 0, 0, 0);
      a0 = __builtin_amdgcn_mfma_f32_16x16x32_bf16(ah1, bh01, a0, 0, 0, 0);
      f32x4 a1 = __builtin_amdgcn_mfma_f32_16x16x32_bf16(ah0, bh10, z, 0, 0, 0);
      a1 = __builtin_amdgcn_mfma_f32_16x16x32_bf16(ah1, bh11, a1, 0, 0, 0);

      const int c0 = cb + st * 16 + quad * 4;
      const float mx0 = fmaxf(fmaxf(a0[0], a0[1]), fmaxf(a0[2], a0[3]));
      if (mx0 >= T0) {
        const int m0 = (a0[0] >= T0) | ((a0[1] >= T0) << 1) |
                       ((a0[2] >= T0) << 2) | ((a0[3] >= T0) << 3);
        int slot = atomicAdd(&lcnt[rl0], __popc(m0));  // LDS atomic
#pragma unroll
        for (int r = 0; r < 4; ++r)
          if (m0 & (1 << r)) {
            if (slot < LCAP) lst[rl0][slot] = (ushort_t)(c0 + r);
            ++slot;
          }
      }
      const float mx1 = fmaxf(fmaxf(a1[0], a1[1]), fmaxf(a1[2], a1[3]));
      if (mx1 >= T1) {
        const int m1 = (a1[0] >= T1) | ((a1[1] >= T1) << 1) |
                       ((a1[2] >= T1) << 2) | ((a1[3] >= T1) << 3);
        int slot = atomicAdd(&lcnt[rl1], __popc(m1));
#pragma unroll
        for (int r = 0; r < 4; ++r)
          if (m1 & (1 << r)) {
            if (slot < LCAP) lst[rl1][slot] = (ushort_t)(c0 + r);
            ++slot;
          }
      }
    }
    __syncthreads();  // readers done before next stage overwrites
  }
  // flush: one global reservation per row, 128 rows by threads 0..127
  if (tid < 128) {
    const int row = rb * 128 + tid;
    const int cnt = min(lcnt[tid], LCAP);
    int base = atomicAdd(rowcnt + row, cnt);
    for (int j = 0; j < cnt; ++j) {
      const int gs = base + j;
      if (gs < MAXC) cidx[(size_t)row * MAXC + gs] = (int)lst[tid][j];
    }
  }
}

// ---------------- K3: exact fp32 dots on candidates + top-16 + gather + mean ----------------
// wave per row; grid NROWS/4 = 4608 blocks x 4 waves. Barrier-free waves.
// (r11, frozen)
__global__ __launch_bounds__(256) void k_merge_gather(
    const float* __restrict__ nf, const int* __restrict__ cidx,
    const int* __restrict__ rowcnt, float* __restrict__ corr) {
  __shared__ ushort_t selc[4][TK];
  const int wave = threadIdx.x >> 6, lane = threadIdx.x & 63;
  const int row = blockIdx.x * 4 + wave;
  const int b = row >= NPIX;
  const int rl = row - b * NPIX;
  const float* nfb = nf + (size_t)b * NPIX * RC;

  // issue earliest: candidate index + count (everything downstream depends)
  const int cv = cidx[(size_t)row * MAXC + lane];
  const int C = min(rowcnt[row], MAXC);

  if (lane < TK) selc[wave][lane] = (ushort_t)rl;  // same-wave pad init

  float4 rv[16];
  const float4* r4 = (const float4*)(nf + (size_t)row * RC);
#pragma unroll
  for (int i = 0; i < 16; ++i) rv[i] = r4[i];  // broadcast loads

  unsigned long long k0 = 0;
  int c0;
  {
    c0 = (lane < C) ? cv : rl;
    const float4* g = (const float4*)(nfb + (size_t)c0 * RC);
    float s = 0.f;
#pragma unroll
    for (int i = 0; i < 16; ++i) {
      float4 a = g[i];
      s += a.x * rv[i].x + a.y * rv[i].y + a.z * rv[i].z + a.w * rv[i].w;
    }
    if (lane < C)
      k0 = ((unsigned long long)ordu(s) << 32) | (uint_t)(~(uint_t)c0);
  }

  if (C <= 64) {  // common path, wave-uniform branch
    unsigned long long thr = 0;
#pragma unroll
    for (int bit = 63; bit >= 0; --bit) {
      const unsigned long long cand = thr | (1ull << bit);
      if (__popcll(__ballot(k0 >= cand)) >= TK) thr = cand;
    }
    if (thr != 0) {
      const unsigned long long ml = (lane == 0) ? 0ull : (~0ull >> (64 - lane));
      const unsigned long long b0 = __ballot(k0 >= thr);
      if (k0 >= thr) {
        const int r = __popcll(b0 & ml);
        if (r < TK) selc[wave][r] = (ushort_t)c0;
      }
    }
  } else {  // heavy rows, rare: second phase
    unsigned long long k1 = 0;
    int c1;
    {
      c1 = (64 + lane < C) ? cidx[(size_t)row * MAXC + 64 + lane] : rl;
      const float4* g = (const float4*)(nfb + (size_t)c1 * RC);
      float s = 0.f;
#pragma unroll
      for (int i = 0; i < 16; ++i) {
        float4 a = g[i];
        s += a.x * rv[i].x + a.y * rv[i].y + a.z * rv[i].z + a.w * rv[i].w;
      }
      if (64 + lane < C)
        k1 = ((unsigned long long)ordu(s) << 32) | (uint_t)(~(uint_t)c1);
    }
    unsigned long long thr = 0;
#pragma unroll
    for (int bit = 63; bit >= 0; --bit) {
      const unsigned long long cand = thr | (1ull << bit);
      const int cnt = __popcll(__ballot(k0 >= cand)) + __popcll(__ballot(k1 >= cand));
      if (cnt >= TK) thr = cand;
    }
    if (thr != 0) {
      const unsigned long long ml = (lane == 0) ? 0ull : (~0ull >> (64 - lane));
      const unsigned long long b0 = __ballot(k0 >= thr);
      const unsigned long long b1 = __ballot(k1 >= thr);
      const int n0 = __popcll(b0);
      if (k0 >= thr) {
        const int r = __popcll(b0 & ml);
        if (r < TK) selc[wave][r] = (ushort_t)c0;
      }
      if (k1 >= thr) {
        const int r = n0 + __popcll(b1 & ml);
        if (r < TK) selc[wave][r] = (ushort_t)c1;
      }
    }
  }

  // wave-order LDS: writes above precede reads below in program order;
  // compiler fence pins ordering (no cross-wave sharing -> no barrier).
  asm volatile("" ::: "memory");

  float acc = 0.f;
#pragma unroll
  for (int t = 0; t < TK; ++t)
    acc += nfb[(size_t)selc[wave][t] * RC + lane];  // coalesced 256B per t
  corr[(size_t)row * RC + lane] = acc * 0.0625f;
}

// ---------------- K4: proj back to C channels + residual add ----------------
// grid: 144 pixgroups(128) x 8 channel-eighths = 1152 blocks x 128 threads
// (r12, frozen)
__global__ __launch_bounds__(128) void k_proj_add(
    const float* __restrict__ x, const float* __restrict__ wp,
    const float* __restrict__ corr, float* __restrict__ out) {
  const int pg = blockIdx.x >> 3, cq = blockIdx.x & 7;
  const int tid = threadIdx.x;  // 0..127

  __shared__ float wl[32 * RC];  // 8 KB
  {
    const float4* src = (const float4*)(wp + (size_t)cq * 32 * RC);
    float4* dst = (float4*)wl;
#pragma unroll
    for (int i = 0; i < 4; ++i) dst[i * 128 + tid] = src[i * 128 + tid];
  }

  const int p = pg * 128 + tid;  // 144*128 = NROWS
  const int b = p >= NPIX;
  const int n = p - b * NPIX;

  float4 cr[16];
  const float4* c4 = (const float4*)(corr + (size_t)p * RC);
#pragma unroll
  for (int i = 0; i < 16; ++i) cr[i] = c4[i];
  __syncthreads();

  const size_t xb = (size_t)b * NC * NPIX + n;
  for (int cl = 0; cl < 32; ++cl) {
    const float4* w4 = (const float4*)(wl + cl * RC);  // broadcast
    float s = 0.f;
#pragma unroll
    for (int i = 0; i < 16; ++i) {
      float4 w = w4[i];
      s += w.x * cr[i].x + w.y * cr[i].y + w.z * cr[i].z + w.w * cr[i].w;
    }
    const int c = cq * 32 + cl;
    const size_t oi = xb + (size_t)c * NPIX;
    out[oi] = x[oi] + s;  // coalesced
  }
}

extern "C" void kernel_launch(void* const* d_in, const int* in_sizes, int n_in,
                              void* d_out, int out_size, void* d_ws, size_t ws_size,
                              hipStream_t stream) {
  const float* x = (const float*)d_in[0];
  const float* wr = (const float*)d_in[1];
  const float* wp = (const float*)d_in[2];
  float* out = (float*)d_out;

  char* ws = (char*)d_ws;
  // region1 (18,874,368 B) time-shares: tmax (sim_max->thresh, 7.1 MB),
  // corr (merge->proj).
  float* tmax = (float*)ws;
  float* corr = (float*)ws;
  float* nf = (float*)(ws + 18874368);
  ushort_t* nf_hi = (ushort_t*)(ws + 23592960);
  float* Tb = (float*)(ws + 25952256);
  int* rowcnt = (int*)(ws + 26025984);
  int* cidx = (int*)(ws + 26099712);
  // total 35,536,896 B

  hipLaunchKernelGGL(k_reduce_norm, dim3(288), dim3(256), 0, stream, x, wr, nf, nf_hi);
  hipLaunchKernelGGL(k_sim_max, dim3(144 * NQ), dim3(256), 0, stream, nf_hi, tmax);
  hipLaunchKernelGGL(k_thresh, dim3(NROWS / 4), dim3(256), 0, stream, tmax, Tb, rowcnt);
  hipLaunchKernelGGL(k_collect, dim3(144 * NQ), dim3(256), 0, stream,
                     nf_hi, Tb, cidx, rowcnt);
  hipLaunchKernelGGL(k_merge_gather, dim3(NROWS / 4), dim3(256), 0, stream,
                     nf, cidx, rowcnt, corr);
  hipLaunchKernelGGL(k_proj_add, dim3(1152), dim3(128), 0, stream, x, wp, corr, out);
}